// Round 12
// baseline (58.311 us; speedup 1.0000x reference)
//
#include <hip/hip_runtime.h>

typedef __attribute__((ext_vector_type(8))) int   i32x8;
typedef __attribute__((ext_vector_type(4))) float f32x4;
typedef unsigned int uint32;

constexpr int N = 16384;
constexpr int K = 1024;
constexpr int M = 1024;

#define FENCE() asm volatile("" ::: "memory")
#define WAITLGKM0_PIN()                                    \
    do {                                                   \
        asm volatile("s_waitcnt lgkmcnt(0)" ::: "memory"); \
        __builtin_amdgcn_sched_barrier(0);                 \
    } while (0)
#define BAR()                          \
    do {                               \
        FENCE();                       \
        __builtin_amdgcn_s_barrier();  \
        FENCE();                       \
    } while (0)

// pack 4 f32 -> 4 OCP e4m3 bytes (k-ascending), saturating
__device__ inline uint32 pack4_fp8(float a, float b, float c, float d) {
    int v = __builtin_amdgcn_cvt_pk_fp8_f32(a, b, 0, false);   // bytes 0,1
    v = __builtin_amdgcn_cvt_pk_fp8_f32(c, d, v, true);        // bytes 2,3
    return (uint32)v;
}

// ---------------------------------------------------------------------------
// prep_mu: one block per mu row m. Writes W in MFMA-FRAGMENT layout Bp
// (verified R10), mmh[m] = -0.5*sum(mu_n^2*inv_std); block 0 also emits
// inv_std[] for the fused gemm's xx computation.
// ---------------------------------------------------------------------------
__global__ void prep_mu(const float* __restrict__ mu, const float* __restrict__ stdv,
                        unsigned char* __restrict__ Bp, float* __restrict__ mmh,
                        float* __restrict__ istd) {
    int m = blockIdx.x;
    int t = threadIdx.x;
    float4 v = ((const float4*)(mu + (size_t)m * K))[t];
    float4 s = ((const float4*)stdv)[t];
    float ix = 1.0f / s.x, iy = 1.0f / s.y, iz = 1.0f / s.z, iw = 1.0f / s.w;
    if (m == 0) {
        float4* o = (float4*)(istd + t * 4);
        *o = make_float4(ix, iy, iz, iw);
    }
    float sum2  = v.x * v.x + v.y * v.y + v.z * v.z + v.w * v.w;
    float sum2w = v.x * v.x * ix + v.y * v.y * iy + v.z * v.z * iz + v.w * v.w * iw;
    for (int off = 32; off > 0; off >>= 1) {
        sum2  += __shfl_down(sum2, off, 64);
        sum2w += __shfl_down(sum2w, off, 64);
    }
    __shared__ float r2[4], r2w[4];
    __shared__ float s_scale;
    int lane = t & 63, w = t >> 6;
    if (lane == 0) { r2[w] = sum2; r2w[w] = sum2w; }
    __syncthreads();
    if (t == 0) {
        float tot2  = r2[0] + r2[1] + r2[2] + r2[3];
        float tot2w = r2w[0] + r2w[1] + r2w[2] + r2w[3];
        mmh[m] = -0.5f * tot2w / tot2;
        s_scale = rsqrtf(tot2) * 0.25f;        // fold the 1/4 fp8-range scale
    }
    __syncthreads();
    float sc = s_scale;
    int col0 = t * 4;
    int kt = col0 >> 7;
    int lk = (col0 >> 5) & 3;
    int j  = col0 & 31;
    int fl = (m & 15) + lk * 16;
    int g  = m >> 4;
    uint32* dst = (uint32*)(Bp + ((size_t)((g * 8 + kt) * 64 + fl)) * 32 + j);
    *dst = pack4_fp8(v.x * ix * sc, v.y * iy * sc, v.z * iz * sc, v.w * iw * sc);
}

// ---------------------------------------------------------------------------
// FUSED convert+GEMM. 128x128 tile, 4 waves (2x2), BK=128 bytes, 8 K-tiles.
// Each block converts its OWN tn-panel slice f32->fp8 (reg-staged, ds_write
// swizzled both-sides per rule 21) and accumulates xx locally — prep_x and
// the xb8 round-trip are gone. The 8 tm-blocks per panel are co-scheduled on
// one XCD (T1 swizzle) so x f32 is HBM-read once, L2-served 7x.
// B from fragment-layout Bp direct to regs (L2-resident, R10-verified).
// NO asm vmcnt anywhere: reg-staged loads are plain dataflow (replay-safe).
// C = 4*(A8*B'^T) + xx[row] + mmh[col]
// ---------------------------------------------------------------------------
#define ATILE 16384                    // 128 rows x 128 B

__global__ __launch_bounds__(256, 2) void gemm_ep(
    const float* __restrict__ x, const unsigned char* __restrict__ Bp,
    const float* __restrict__ istd, const float* __restrict__ mmh,
    float* __restrict__ C) {
    __shared__ unsigned char Als[2 * ATILE];   // 32 KiB (reused for xx reduce)

    int t = threadIdx.x;
    int lane = t & 63;
    int wave = t >> 6;
    int wr = wave >> 1;          // 0..1
    int wc = wave & 1;           // 0..1
    int r  = lane & 15;
    int lk = lane >> 4;          // k-slot 0..3 (32B each)

    // T1: XCD swizzle, nwg=1024 (bijective). 8 tm-blocks of a tn contiguous.
    int bid = blockIdx.x;
    int swz = (bid & 7) * 128 + (bid >> 3);
    int tn = swz >> 3;           // 0..127
    int tm = swz & 7;            // 0..7

    const float* Xp = x + (size_t)tn * 128 * K;
    const unsigned char* Bw = Bp + (size_t)(tm * 8 + wc * 4) * 16384 + (size_t)lane * 32;

    // conversion mapping: thread covers 8 rows x 8 cols per tile
    int colblk = t & 15;         // cols colblk*8 .. +7 (tile-local)
    int rowblk = t >> 4;         // rows rowblk*8 .. +7
    const float* xthr = Xp + (size_t)rowblk * 8 * K + colblk * 8;

    f32x4 acc[4][4] = {};
    float xxp[8] = {0.f, 0.f, 0.f, 0.f, 0.f, 0.f, 0.f, 0.f};
    uint32 pk[16];
    float4 xa0, xa1, xa2, xa3, xa4, xa5, xa6, xa7, sda, sdb;
    i32x8 af[4], bf[4];

    // issue 8 x-float4 (4 rows) for tile kt2, half h; istd loaded at h==0
#define ISSUE_H(kt2_, h_)                                                      \
    {                                                                          \
        const float* gx_ = xthr + (size_t)(h_) * 4 * K + (size_t)(kt2_) * 128; \
        xa0 = *(const float4*)(gx_ + 0 * K);                                   \
        xa1 = *(const float4*)(gx_ + 0 * K + 4);                               \
        xa2 = *(const float4*)(gx_ + 1 * K);                                   \
        xa3 = *(const float4*)(gx_ + 1 * K + 4);                               \
        xa4 = *(const float4*)(gx_ + 2 * K);                                   \
        xa5 = *(const float4*)(gx_ + 2 * K + 4);                               \
        xa6 = *(const float4*)(gx_ + 3 * K);                                   \
        xa7 = *(const float4*)(gx_ + 3 * K + 4);                               \
        if ((h_) == 0) {                                                       \
            sda = *(const float4*)(istd + (kt2_) * 128 + colblk * 8);          \
            sdb = *(const float4*)(istd + (kt2_) * 128 + colblk * 8 + 4);      \
        }                                                                      \
    }

#define PROC_ROW(ri_, va_, vb_)                                                \
    xxp[ri_] += va_.x * va_.x * sda.x + va_.y * va_.y * sda.y +                \
                va_.z * va_.z * sda.z + va_.w * va_.w * sda.w +                \
                vb_.x * vb_.x * sdb.x + vb_.y * vb_.y * sdb.y +                \
                vb_.z * vb_.z * sdb.z + vb_.w * vb_.w * sdb.w;                 \
    pk[(ri_) * 2]     = pack4_fp8(va_.x, va_.y, va_.z, va_.w);                 \
    pk[(ri_) * 2 + 1] = pack4_fp8(vb_.x, vb_.y, vb_.z, vb_.w);

#define PROCESS_H(h_)                                                          \
    {                                                                          \
        PROC_ROW((h_) * 4 + 0, xa0, xa1);                                      \
        PROC_ROW((h_) * 4 + 1, xa2, xa3);                                      \
        PROC_ROW((h_) * 4 + 2, xa4, xa5);                                      \
        PROC_ROW((h_) * 4 + 3, xa6, xa7);                                      \
    }

    // ds_write pk (one tile's 8 rows x 8 B) to buf, swizzled (matches AFL)
#define DSW(buf_)                                                              \
    {                                                                          \
        unsigned char* l_ = Als + (buf_) * ATILE;                              \
        _Pragma("unroll")                                                      \
        for (int ri_ = 0; ri_ < 8; ++ri_) {                                    \
            int gr_ = rowblk * 8 + ri_;                                        \
            int ba_ = gr_ * 128 + ((((colblk >> 1)) ^ (gr_ & 7)) << 4) +       \
                      ((colblk & 1) << 3);                                     \
            *(uint2*)(l_ + ba_) = make_uint2(pk[ri_ * 2], pk[ri_ * 2 + 1]);    \
        }                                                                      \
    }

#define BFL(kt_)                                                               \
    _Pragma("unroll")                                                          \
    for (int ni_ = 0; ni_ < 4; ++ni_) {                                        \
        const unsigned char* gb_ =                                             \
            Bw + (size_t)ni_ * 16384 + (size_t)(kt_) * 2048;                   \
        uint4 q0_ = *(const uint4*)gb_;                                        \
        uint4 q1_ = *(const uint4*)(gb_ + 16);                                 \
        bf[ni_][0] = q0_.x; bf[ni_][1] = q0_.y;                                \
        bf[ni_][2] = q0_.z; bf[ni_][3] = q0_.w;                                \
        bf[ni_][4] = q1_.x; bf[ni_][5] = q1_.y;                                \
        bf[ni_][6] = q1_.z; bf[ni_][7] = q1_.w;                                \
    }

#define AFL(buf_)                                                              \
    {                                                                          \
        const unsigned char* As_ = Als + (buf_) * ATILE;                       \
        _Pragma("unroll")                                                      \
        for (int mi_ = 0; mi_ < 4; ++mi_) {                                    \
            int row_ = wr * 64 + mi_ * 16 + r;                                 \
            uint4 q0_ = *(const uint4*)&As_[(row_ << 7) +                      \
                        ((((lk << 1) | 0) ^ (r & 7)) << 4)];                   \
            uint4 q1_ = *(const uint4*)&As_[(row_ << 7) +                      \
                        ((((lk << 1) | 1) ^ (r & 7)) << 4)];                   \
            af[mi_][0] = q0_.x; af[mi_][1] = q0_.y;                            \
            af[mi_][2] = q0_.z; af[mi_][3] = q0_.w;                            \
            af[mi_][4] = q1_.x; af[mi_][5] = q1_.y;                            \
            af[mi_][6] = q1_.z; af[mi_][7] = q1_.w;                            \
        }                                                                      \
    }

#define MFMA_H(h_)                                                             \
    __builtin_amdgcn_s_setprio(1);                                             \
    _Pragma("unroll")                                                          \
    for (int mi_ = (h_) * 2; mi_ < (h_) * 2 + 2; ++mi_)                        \
        _Pragma("unroll")                                                      \
        for (int ni_ = 0; ni_ < 4; ++ni_)                                      \
            acc[mi_][ni_] = __builtin_amdgcn_mfma_scale_f32_16x16x128_f8f6f4(  \
                af[mi_], bf[ni_], acc[mi_][ni_],                               \
                0, 0, 0, 0x7f7f7f7f, 0, 0x7f7f7f7f);                           \
    __builtin_amdgcn_s_setprio(0);

    // ---- prologue: convert T0 -> buf0; convert T1 into pk (held in regs)
    ISSUE_H(0, 0); PROCESS_H(0);
    ISSUE_H(0, 1); PROCESS_H(1);
    DSW(0);
    ISSUE_H(1, 0); PROCESS_H(0);
    ISSUE_H(1, 1); PROCESS_H(1);
    WAITLGKM0_PIN();
    BAR();

    for (int kt = 0; kt < 8; ++kt) {
        int cur = kt & 1;
        if (kt < 7) DSW(cur ^ 1);          // write T(kt+1); buf^1 reads done kt-1
        BFL(kt);
        if (kt < 6) ISSUE_H(kt + 2, 0);
        AFL(cur);
        MFMA_H(0);
        if (kt < 6) { PROCESS_H(0); ISSUE_H(kt + 2, 1); }
        MFMA_H(1);
        if (kt < 6) PROCESS_H(1);
        WAITLGKM0_PIN();                   // ds_writes + af reads complete
        BAR();
    }

    // ---- xx reduce in LDS (Als reusable now): xsc[128][17], xrow[128]
    float* xsc = (float*)Als;
#pragma unroll
    for (int ri = 0; ri < 8; ++ri)
        xsc[(rowblk * 8 + ri) * 17 + colblk] = xxp[ri];
    WAITLGKM0_PIN();
    BAR();
    float* xrow = (float*)(Als + 128 * 17 * 4);
    if (t < 128) {
        float s_ = 0.f;
#pragma unroll
        for (int c = 0; c < 16; ++c) s_ += xsc[t * 17 + c];
        xrow[t] = -0.5f * s_;
    }
    WAITLGKM0_PIN();
    BAR();

    // ---- epilogue: C = 4*acc + xrow[row] + mmh[col]
    int rowb = tn * 128 + wr * 64;
    int colb = tm * 128 + wc * 64;
#pragma unroll
    for (int mi = 0; mi < 4; ++mi) {
        float4 xh = *(const float4*)&xrow[wr * 64 + mi * 16 + lk * 4];
#pragma unroll
        for (int ni = 0; ni < 4; ++ni) {
            int col = colb + ni * 16 + r;
            float mh = mmh[col];
            C[(size_t)(rowb + mi * 16 + lk * 4 + 0) * M + col] = acc[mi][ni][0] * 4.0f + xh.x + mh;
            C[(size_t)(rowb + mi * 16 + lk * 4 + 1) * M + col] = acc[mi][ni][1] * 4.0f + xh.y + mh;
            C[(size_t)(rowb + mi * 16 + lk * 4 + 2) * M + col] = acc[mi][ni][2] * 4.0f + xh.z + mh;
            C[(size_t)(rowb + mi * 16 + lk * 4 + 3) * M + col] = acc[mi][ni][3] * 4.0f + xh.w + mh;
        }
    }
#undef ISSUE_H
#undef PROC_ROW
#undef PROCESS_H
#undef DSW
#undef BFL
#undef AFL
#undef MFMA_H
}

extern "C" void kernel_launch(void* const* d_in, const int* in_sizes, int n_in,
                              void* d_out, int out_size, void* d_ws, size_t ws_size,
                              hipStream_t stream) {
    const float* x    = (const float*)d_in[0];
    const float* mu   = (const float*)d_in[1];
    const float* stdv = (const float*)d_in[2];
    float* out = (float*)d_out;

    char* ws = (char*)d_ws;
    unsigned char* Bp  = (unsigned char*)ws;                        // M*K = 1 MB (fragment layout)
    float* mmh  = (float*)(ws + (size_t)M * K);                     // 4 KB
    float* istd = (float*)(ws + (size_t)M * K + 4096);              // 4 KB

    prep_mu<<<M, 256, 0, stream>>>(mu, stdv, Bp, mmh, istd);
    gemm_ep<<<(N / 128) * (M / 128), 256, 0, stream>>>(x, Bp, istd, mmh, out);
}